// Round 1
// baseline (104.061 us; speedup 1.0000x reference)
//
#include <hip/hip_runtime.h>
#include <hip/hip_bf16.h>

// GCNConvAdj: out = D^-1/2 (A+I) D^-1/2 (x W) + b
// B=8, N=2048, F_IN=F_OUT=256. All f32 in/out; internals bf16 MFMA.
#define BB 8
#define NN 2048
#define FF 256

typedef __attribute__((ext_vector_type(8))) short short8;
typedef __attribute__((ext_vector_type(4))) short short4v;
typedef __attribute__((ext_vector_type(4))) float f32x4;
typedef __hip_bfloat16 bf16;

__device__ inline short f2bf(float x) {
  // RNE f32->bf16 (inputs finite)
  unsigned u = __builtin_bit_cast(unsigned, x);
  unsigned r = (u + 0x7fffu + ((u >> 16) & 1u)) >> 16;
  return (short)r;
}

// ---------------- kernel 1: degree -> dis = rsqrt(rowsum(adj)+1) ------------
__global__ __launch_bounds__(256)
void deg_kernel(const float* __restrict__ adj, float* __restrict__ dis) {
  int wid = threadIdx.x >> 6, lane = threadIdx.x & 63;
  int row = blockIdx.x * 4 + wid;              // 0 .. BB*NN-1
  const float4* a4 = reinterpret_cast<const float4*>(adj + (size_t)row * NN);
  float s = 0.f;
#pragma unroll
  for (int i = 0; i < 8; i++) {
    float4 v = a4[lane + 64 * i];
    s += v.x + v.y + v.z + v.w;
  }
#pragma unroll
  for (int off = 32; off; off >>= 1) s += __shfl_down(s, off, 64);
  if (lane == 0) dis[row] = rsqrtf(s + 1.0f);
}

// ---------------- kernel 2: WT[o][k] = bf16(W[k][o]) ------------------------
__global__ __launch_bounds__(256)
void wt_kernel(const float* __restrict__ W, bf16* __restrict__ WT) {
  int t = blockIdx.x * 256 + threadIdx.x;      // 0 .. FF*FF-1
  int k = t >> 8, o = t & 255;
  short v = f2bf(W[k * FF + o]);
  *reinterpret_cast<short*>(WT + (size_t)o * FF + k) = v;
}

// ---------------- kernel 3: gT[b][o][m] = dis[m] * (x@W)[m][o] (bf16) -------
__global__ __launch_bounds__(256)
void gemm1_kernel(const float* __restrict__ x, const bf16* __restrict__ WT,
                  const float* __restrict__ dis, bf16* __restrict__ gT) {
  __shared__ bf16 lA[128][40];
  __shared__ bf16 lB[128][40];
  int bid = blockIdx.x;                        // 256 blocks
  int mtile = bid >> 1, otile = bid & 1;
  int m0 = mtile * 128;                        // flat row in [0,16384)
  int o0 = otile * 128;
  int t = threadIdx.x, wid = t >> 6, lane = t & 63;
  int wr = wid >> 1, wc = wid & 1;
  int srow = t >> 1, sseg = t & 1;
  const int r16 = lane & 15, kb = lane >> 4;

  f32x4 acc[4][4];
#pragma unroll
  for (int i = 0; i < 4; i++)
#pragma unroll
    for (int j = 0; j < 4; j++) acc[i][j] = (f32x4){0.f, 0.f, 0.f, 0.f};

  for (int k0 = 0; k0 < FF; k0 += 32) {
    // stage A: x[m0+srow][k0+sseg*16 .. +16) f32 -> bf16
    {
      const float4* ap = reinterpret_cast<const float4*>(
          x + (size_t)(m0 + srow) * FF + k0 + sseg * 16);
      float arr[16];
      float4 v0 = ap[0], v1 = ap[1], v2 = ap[2], v3 = ap[3];
      arr[0]=v0.x; arr[1]=v0.y; arr[2]=v0.z; arr[3]=v0.w;
      arr[4]=v1.x; arr[5]=v1.y; arr[6]=v1.z; arr[7]=v1.w;
      arr[8]=v2.x; arr[9]=v2.y; arr[10]=v2.z; arr[11]=v2.w;
      arr[12]=v3.x; arr[13]=v3.y; arr[14]=v3.z; arr[15]=v3.w;
      short8 w0, w1;
#pragma unroll
      for (int e = 0; e < 8; e++) { w0[e] = f2bf(arr[e]); w1[e] = f2bf(arr[8 + e]); }
      *reinterpret_cast<short8*>(&lA[srow][sseg * 16]) = w0;
      *reinterpret_cast<short8*>(&lA[srow][sseg * 16 + 8]) = w1;
    }
    // stage B: WT[o0+srow][k0+sseg*16 ..) bf16 direct
    {
      const short8* bp = reinterpret_cast<const short8*>(
          WT + (size_t)(o0 + srow) * FF + k0 + sseg * 16);
      *reinterpret_cast<short8*>(&lB[srow][sseg * 16]) = bp[0];
      *reinterpret_cast<short8*>(&lB[srow][sseg * 16 + 8]) = bp[1];
    }
    __syncthreads();
    short8 af[4], bfr[4];
#pragma unroll
    for (int mf = 0; mf < 4; mf++)
      af[mf] = *reinterpret_cast<const short8*>(&lA[wr * 64 + mf * 16 + r16][kb * 8]);
#pragma unroll
    for (int nf = 0; nf < 4; nf++)
      bfr[nf] = *reinterpret_cast<const short8*>(&lB[wc * 64 + nf * 16 + r16][kb * 8]);
#pragma unroll
    for (int mf = 0; mf < 4; mf++)
#pragma unroll
      for (int nf = 0; nf < 4; nf++)
        acc[mf][nf] = __builtin_amdgcn_mfma_f32_16x16x32_bf16(af[mf], bfr[nf], acc[mf][nf], 0, 0, 0);
    __syncthreads();
  }

  // epilogue: gT[b][o][m] = bf16(acc * dis[m])
  int b = m0 >> 11;
#pragma unroll
  for (int mf = 0; mf < 4; mf++) {
    int mloc = wr * 64 + mf * 16 + (lane >> 4) * 4;  // 4 consecutive rows
    int mg = m0 + mloc;
    float4 d4 = *reinterpret_cast<const float4*>(dis + mg);
#pragma unroll
    for (int nf = 0; nf < 4; nf++) {
      int o = o0 + wc * 64 + nf * 16 + r16;
      f32x4 v = acc[mf][nf];
      short4v w;
      w[0] = f2bf(v[0] * d4.x);
      w[1] = f2bf(v[1] * d4.y);
      w[2] = f2bf(v[2] * d4.z);
      w[3] = f2bf(v[3] * d4.w);
      *reinterpret_cast<short4v*>(gT + ((size_t)b * FF + o) * NN + (mg & (NN - 1))) = w;
    }
  }
}

// ---------------- kernel 4: out[b][n][o] = dis[n]*((adj+I)@g)[n][o] + bias --
__global__ __launch_bounds__(256)
void gemm2_kernel(const float* __restrict__ adj, const bf16* __restrict__ gT,
                  const float* __restrict__ dis, const float* __restrict__ bias,
                  float* __restrict__ out) {
  __shared__ bf16 lA[128][40];
  __shared__ bf16 lB[128][40];
  int bid = blockIdx.x;  // 256
  // pair-swizzle: the two o-tiles of one (batch,mtile) land 8 apart -> same XCD
  int c = bid >> 4, j = bid & 7, sub = (bid >> 3) & 1;
  int group = c * 8 + j;        // 0..127
  int batch = group >> 4;       // 0..7
  int mtile = group & 15;       // 0..15
  int n0 = mtile * 128, o0 = sub * 128;
  const float* A = adj + (size_t)batch * NN * NN;
  const bf16* Bt = gT + (size_t)batch * FF * NN;

  int t = threadIdx.x, wid = t >> 6, lane = t & 63;
  int wr = wid >> 1, wc = wid & 1;
  int srow = t >> 1, sseg = t & 1;
  const int r16 = lane & 15, kb = lane >> 4;

  f32x4 acc[4][4];
#pragma unroll
  for (int i = 0; i < 4; i++)
#pragma unroll
    for (int j2 = 0; j2 < 4; j2++) acc[i][j2] = (f32x4){0.f, 0.f, 0.f, 0.f};

  for (int k0 = 0; k0 < NN; k0 += 32) {
    // stage A: adj[n0+srow][k0+sseg*16 ..) f32 -> bf16, +1 on diagonal
    {
      const float4* ap = reinterpret_cast<const float4*>(
          A + (size_t)(n0 + srow) * NN + k0 + sseg * 16);
      float arr[16];
      float4 v0 = ap[0], v1 = ap[1], v2 = ap[2], v3 = ap[3];
      arr[0]=v0.x; arr[1]=v0.y; arr[2]=v0.z; arr[3]=v0.w;
      arr[4]=v1.x; arr[5]=v1.y; arr[6]=v1.z; arr[7]=v1.w;
      arr[8]=v2.x; arr[9]=v2.y; arr[10]=v2.z; arr[11]=v2.w;
      arr[12]=v3.x; arr[13]=v3.y; arr[14]=v3.z; arr[15]=v3.w;
      if (k0 + 32 > n0 && k0 < n0 + 128) {   // block-uniform: diagonal in tile?
        int grow = n0 + srow, gcol0 = k0 + sseg * 16;
#pragma unroll
        for (int e = 0; e < 16; e++)
          if (gcol0 + e == grow) arr[e] += 1.0f;
      }
      short8 w0, w1;
#pragma unroll
      for (int e = 0; e < 8; e++) { w0[e] = f2bf(arr[e]); w1[e] = f2bf(arr[8 + e]); }
      *reinterpret_cast<short8*>(&lA[srow][sseg * 16]) = w0;
      *reinterpret_cast<short8*>(&lA[srow][sseg * 16 + 8]) = w1;
    }
    // stage B: gT[o0+srow][k0+sseg*16 ..) bf16 direct
    {
      const short8* bp = reinterpret_cast<const short8*>(
          Bt + (size_t)(o0 + srow) * NN + k0 + sseg * 16);
      *reinterpret_cast<short8*>(&lB[srow][sseg * 16]) = bp[0];
      *reinterpret_cast<short8*>(&lB[srow][sseg * 16 + 8]) = bp[1];
    }
    __syncthreads();
    short8 af[4], bfr[4];
#pragma unroll
    for (int mf = 0; mf < 4; mf++)
      af[mf] = *reinterpret_cast<const short8*>(&lA[wr * 64 + mf * 16 + r16][kb * 8]);
#pragma unroll
    for (int nf = 0; nf < 4; nf++)
      bfr[nf] = *reinterpret_cast<const short8*>(&lB[wc * 64 + nf * 16 + r16][kb * 8]);
#pragma unroll
    for (int mf = 0; mf < 4; mf++)
#pragma unroll
      for (int nf = 0; nf < 4; nf++)
        acc[mf][nf] = __builtin_amdgcn_mfma_f32_16x16x32_bf16(af[mf], bfr[nf], acc[mf][nf], 0, 0, 0);
    __syncthreads();
  }

  // epilogue: out = dis[n]*acc + bias[o]
  float bv[4];
#pragma unroll
  for (int nf = 0; nf < 4; nf++) bv[nf] = bias[o0 + wc * 64 + nf * 16 + r16];
#pragma unroll
  for (int mf = 0; mf < 4; mf++) {
    int nloc = wr * 64 + mf * 16 + (lane >> 4) * 4;
    int ng = n0 + nloc;
    float4 d4 = *reinterpret_cast<const float4*>(dis + (size_t)batch * NN + ng);
#pragma unroll
    for (int nf = 0; nf < 4; nf++) {
      int o = o0 + wc * 64 + nf * 16 + r16;
      f32x4 v = acc[mf][nf];
      float* op = out + ((size_t)batch * NN + ng) * FF + o;
      op[0 * FF] = v[0] * d4.x + bv[nf];
      op[1 * FF] = v[1] * d4.y + bv[nf];
      op[2 * FF] = v[2] * d4.z + bv[nf];
      op[3 * FF] = v[3] * d4.w + bv[nf];
    }
  }
}

extern "C" void kernel_launch(void* const* d_in, const int* in_sizes, int n_in,
                              void* d_out, int out_size, void* d_ws, size_t ws_size,
                              hipStream_t stream) {
  const float* x    = (const float*)d_in[0];
  const float* adj  = (const float*)d_in[1];
  const float* W    = (const float*)d_in[2];
  const float* bias = (const float*)d_in[3];
  float* out = (float*)d_out;

  char* ws = (char*)d_ws;
  float* dis = (float*)ws;                          // 16384 f32 = 64 KB
  bf16* WT   = (bf16*)(ws + 65536);                 // 65536 bf16 = 128 KB
  bf16* gT   = (bf16*)(ws + 65536 + 131072);        // 8,388,608 B

  deg_kernel<<<BB * NN / 4, 256, 0, stream>>>(adj, dis);
  wt_kernel<<<FF * FF / 256, 256, 0, stream>>>(W, WT);
  gemm1_kernel<<<256, 256, 0, stream>>>(x, WT, dis, gT);
  gemm2_kernel<<<256, 256, 0, stream>>>(adj, gT, dis, bias, out);
}

// Round 2
// 83.628 us; speedup vs baseline: 1.2443x; 1.2443x over previous
//
#include <hip/hip_runtime.h>
#include <hip/hip_bf16.h>

// GCNConvAdj: out = D^-1/2 (A+I) D^-1/2 (x W) + b
// B=8, N=2048, F_IN=F_OUT=256. f32 in/out; bf16 MFMA internals.
// Pipeline: wt (W->WT bf16) ; degconv (deg + adjBF = dis[n]*(A+I) bf16) ;
//           gemm1 (gT = dis[m]*(x@W), bf16, o-major) ; gemm2 (adjBF@gT + b).
#define BB 8
#define NN 2048
#define FF 256

typedef __attribute__((ext_vector_type(8))) short short8;
typedef __attribute__((ext_vector_type(4))) short short4v;
typedef __attribute__((ext_vector_type(4))) float f32x4;
typedef __hip_bfloat16 bf16;

__device__ inline short f2bf(float x) {
  unsigned u = __builtin_bit_cast(unsigned, x);
  unsigned r = (u + 0x7fffu + ((u >> 16) & 1u)) >> 16;
  return (short)r;
}

__device__ inline void gl2lds16(const void* g, void* l) {
  __builtin_amdgcn_global_load_lds((const __attribute__((address_space(1))) void*)g,
                                   (__attribute__((address_space(3))) void*)l, 16, 0, 0);
}

// ---------------- kernel 1: WT[o][k] = bf16(W[k][o]) ------------------------
__global__ __launch_bounds__(256)
void wt_kernel(const float* __restrict__ W, bf16* __restrict__ WT) {
  int t = blockIdx.x * 256 + threadIdx.x;
  int k = t >> 8, o = t & 255;
  *reinterpret_cast<short*>(WT + (size_t)o * FF + k) = f2bf(W[k * FF + o]);
}

// ------- kernel 2: deg + convert: adjBF[r][m] = bf16(dis_r*(adj+I)) ---------
__global__ __launch_bounds__(256)
void degconv_kernel(const float* __restrict__ adj, float* __restrict__ dis,
                    bf16* __restrict__ adjBF) {
  int wid = threadIdx.x >> 6, lane = threadIdx.x & 63;
  int row = blockIdx.x * 4 + wid;                       // 0 .. BB*NN-1
  const float4* a4 = reinterpret_cast<const float4*>(adj + (size_t)row * NN);
  float4 v[8];
  float s = 0.f;
#pragma unroll
  for (int i = 0; i < 8; i++) {
    v[i] = a4[lane + 64 * i];
    s += v[i].x + v[i].y + v[i].z + v[i].w;
  }
#pragma unroll
  for (int off = 1; off < 64; off <<= 1) s += __shfl_xor(s, off, 64);
  float d = rsqrtf(s + 1.0f);                           // +1 from the identity diag
  if (lane == 0) dis[row] = d;
  // fold +I: diagonal element is at col (row % NN)
  int rb = row & (NN - 1);
  int dv = rb >> 2, dl = dv & 63, di = dv >> 6, de = rb & 3;
#pragma unroll
  for (int i = 0; i < 8; i++) {
    if (lane == dl && i == di) {
      float4 t = v[i];
      t.x += (de == 0); t.y += (de == 1); t.z += (de == 2); t.w += (de == 3);
      v[i] = t;
    }
  }
  bf16* orow = adjBF + (size_t)row * NN;
#pragma unroll
  for (int i = 0; i < 8; i++) {
    int c0 = (lane + 64 * i) << 2;
    short4v w;
    w[0] = f2bf(v[i].x * d); w[1] = f2bf(v[i].y * d);
    w[2] = f2bf(v[i].z * d); w[3] = f2bf(v[i].w * d);
    *reinterpret_cast<short4v*>(orow + c0) = w;
  }
}

// ---------------- kernel 3: gT[b][o][m] = dis[m] * (x@W)[m][o] (bf16) -------
__global__ __launch_bounds__(256)
void gemm1_kernel(const float* __restrict__ x, const bf16* __restrict__ WT,
                  const float* __restrict__ dis, bf16* __restrict__ gT) {
  __shared__ bf16 lA[128][40];
  __shared__ bf16 lB[128][40];
  int bid = blockIdx.x;
  int mtile = bid >> 1, otile = bid & 1;
  int m0 = mtile * 128, o0 = otile * 128;
  int t = threadIdx.x, wid = t >> 6, lane = t & 63;
  int wr = wid >> 1, wc = wid & 1;
  int srow = t >> 1, sseg = t & 1;
  const int r16 = lane & 15, kb = lane >> 4;

  f32x4 acc[4][4];
#pragma unroll
  for (int i = 0; i < 4; i++)
#pragma unroll
    for (int j = 0; j < 4; j++) acc[i][j] = (f32x4){0.f, 0.f, 0.f, 0.f};

  for (int k0 = 0; k0 < FF; k0 += 32) {
    {
      const float4* ap = reinterpret_cast<const float4*>(
          x + (size_t)(m0 + srow) * FF + k0 + sseg * 16);
      float arr[16];
      float4 v0 = ap[0], v1 = ap[1], v2 = ap[2], v3 = ap[3];
      arr[0]=v0.x; arr[1]=v0.y; arr[2]=v0.z; arr[3]=v0.w;
      arr[4]=v1.x; arr[5]=v1.y; arr[6]=v1.z; arr[7]=v1.w;
      arr[8]=v2.x; arr[9]=v2.y; arr[10]=v2.z; arr[11]=v2.w;
      arr[12]=v3.x; arr[13]=v3.y; arr[14]=v3.z; arr[15]=v3.w;
      short8 w0, w1;
#pragma unroll
      for (int e = 0; e < 8; e++) { w0[e] = f2bf(arr[e]); w1[e] = f2bf(arr[8 + e]); }
      *reinterpret_cast<short8*>(&lA[srow][sseg * 16]) = w0;
      *reinterpret_cast<short8*>(&lA[srow][sseg * 16 + 8]) = w1;
    }
    {
      const short8* bp = reinterpret_cast<const short8*>(
          WT + (size_t)(o0 + srow) * FF + k0 + sseg * 16);
      *reinterpret_cast<short8*>(&lB[srow][sseg * 16]) = bp[0];
      *reinterpret_cast<short8*>(&lB[srow][sseg * 16 + 8]) = bp[1];
    }
    __syncthreads();
    short8 af[4], bfr[4];
#pragma unroll
    for (int mf = 0; mf < 4; mf++)
      af[mf] = *reinterpret_cast<const short8*>(&lA[wr * 64 + mf * 16 + r16][kb * 8]);
#pragma unroll
    for (int nf = 0; nf < 4; nf++)
      bfr[nf] = *reinterpret_cast<const short8*>(&lB[wc * 64 + nf * 16 + r16][kb * 8]);
#pragma unroll
    for (int mf = 0; mf < 4; mf++)
#pragma unroll
      for (int nf = 0; nf < 4; nf++)
        acc[mf][nf] = __builtin_amdgcn_mfma_f32_16x16x32_bf16(af[mf], bfr[nf], acc[mf][nf], 0, 0, 0);
    __syncthreads();
  }

  int b = m0 >> 11;
#pragma unroll
  for (int mf = 0; mf < 4; mf++) {
    int mloc = wr * 64 + mf * 16 + (lane >> 4) * 4;
    int mg = m0 + mloc;
    float4 d4 = *reinterpret_cast<const float4*>(dis + mg);
#pragma unroll
    for (int nf = 0; nf < 4; nf++) {
      int o = o0 + wc * 64 + nf * 16 + r16;
      f32x4 v = acc[mf][nf];
      short4v w;
      w[0] = f2bf(v[0] * d4.x); w[1] = f2bf(v[1] * d4.y);
      w[2] = f2bf(v[2] * d4.z); w[3] = f2bf(v[3] * d4.w);
      *reinterpret_cast<short4v*>(gT + ((size_t)b * FF + o) * NN + (mg & (NN - 1))) = w;
    }
  }
}

// ------- kernel 4: out[b][n][o] = (adjBF @ gT^T)[n][o] + bias[o] ------------
// m97-style: global_load_lds staging, BK=64, double-buffered LDS,
// XOR slot-swizzle (key = row&7) applied to global source + ds_read addr.
__global__ __launch_bounds__(256)
void gemm2_kernel(const bf16* __restrict__ adjBF, const bf16* __restrict__ gT,
                  const float* __restrict__ bias, float* __restrict__ out) {
  __shared__ __align__(16) bf16 sm[2][2][128 * 64];   // [buf][A/B][row*64+col]
  int bid = blockIdx.x;
  // pair o-tiles of one (batch,mtile) onto the same XCD (bid%8 invariant)
  int c = bid >> 4, j = bid & 7, sub = (bid >> 3) & 1;
  int group = c * 8 + j;
  int batch = group >> 4, mtile = group & 15;
  int n0 = mtile * 128, o0 = sub * 128;
  const bf16* Ab = adjBF + (size_t)batch * NN * NN;
  const bf16* Bt = gT + (size_t)batch * FF * NN;

  int t = threadIdx.x, wid = t >> 6, lane = t & 63;
  int wr = wid >> 1, wc = wid & 1;
  int r16 = lane & 15, kb = lane >> 4;
  int trow = t >> 3, tslot = t & 7;
  int gslot = tslot ^ (trow & 7);      // inverse-swizzled global slot

  const bf16* Ag = Ab + (size_t)(n0 + trow) * NN + 8 * gslot;
  const bf16* Bg = Bt + (size_t)(o0 + trow) * NN + 8 * gslot;

  f32x4 acc[4][4];
#pragma unroll
  for (int i = 0; i < 4; i++)
#pragma unroll
    for (int jj = 0; jj < 4; jj++) acc[i][jj] = (f32x4){0.f, 0.f, 0.f, 0.f};

  auto stage = [&](int buf, int ks) {
    const bf16* ag = Ag + ks * 64;
    const bf16* bg = Bg + ks * 64;
    bf16* la = &sm[buf][0][wid * 512];
    bf16* lb = &sm[buf][1][wid * 512];
#pragma unroll
    for (int q = 0; q < 4; q++) {
      gl2lds16(ag + (size_t)q * 32 * NN, la + q * 2048);
      gl2lds16(bg + (size_t)q * 32 * NN, lb + q * 2048);
    }
  };

  int cur = 0;
  stage(0, 0);
  __syncthreads();
#pragma unroll 1
  for (int ks = 0; ks < NN / 64; ++ks) {
    if (ks + 1 < NN / 64) stage(cur ^ 1, ks + 1);
    const bf16* sa = sm[cur][0];
    const bf16* sb = sm[cur][1];
#pragma unroll
    for (int kk = 0; kk < 2; kk++) {
      short8 af[4], bfr[4];
#pragma unroll
      for (int mf = 0; mf < 4; mf++) {
        int row = wr * 64 + mf * 16 + r16;
        int slot = ((kk << 2) | kb) ^ (row & 7);
        af[mf] = *reinterpret_cast<const short8*>(&sa[row * 64 + slot * 8]);
      }
#pragma unroll
      for (int nf = 0; nf < 4; nf++) {
        int row = wc * 64 + nf * 16 + r16;
        int slot = ((kk << 2) | kb) ^ (row & 7);
        bfr[nf] = *reinterpret_cast<const short8*>(&sb[row * 64 + slot * 8]);
      }
#pragma unroll
      for (int mf = 0; mf < 4; mf++)
#pragma unroll
        for (int nf = 0; nf < 4; nf++)
          acc[mf][nf] = __builtin_amdgcn_mfma_f32_16x16x32_bf16(af[mf], bfr[nf], acc[mf][nf], 0, 0, 0);
    }
    __syncthreads();   // drains vmcnt (prefetch) + protects dbuf swap
    cur ^= 1;
  }

  float bv[4];
#pragma unroll
  for (int nf = 0; nf < 4; nf++) bv[nf] = bias[o0 + wc * 64 + nf * 16 + r16];
#pragma unroll
  for (int mf = 0; mf < 4; mf++) {
    int ng = n0 + wr * 64 + mf * 16 + (lane >> 4) * 4;
    float* op0 = out + ((size_t)batch * NN + ng) * FF;
#pragma unroll
    for (int nf = 0; nf < 4; nf++) {
      int o = o0 + wc * 64 + nf * 16 + r16;
      f32x4 v = acc[mf][nf];
      op0[0 * FF + o] = v[0] + bv[nf];
      op0[1 * FF + o] = v[1] + bv[nf];
      op0[2 * FF + o] = v[2] + bv[nf];
      op0[3 * FF + o] = v[3] + bv[nf];
    }
  }
}

extern "C" void kernel_launch(void* const* d_in, const int* in_sizes, int n_in,
                              void* d_out, int out_size, void* d_ws, size_t ws_size,
                              hipStream_t stream) {
  const float* x    = (const float*)d_in[0];
  const float* adj  = (const float*)d_in[1];
  const float* W    = (const float*)d_in[2];
  const float* bias = (const float*)d_in[3];
  float* out = (float*)d_out;

  char* ws = (char*)d_ws;
  float* dis  = (float*)ws;                              // 64 KB
  bf16* WT    = (bf16*)(ws + (64 << 10));                // 128 KB
  bf16* gT    = (bf16*)(ws + (192 << 10));               // 8 MB
  bf16* adjBF = (bf16*)(ws + (192 << 10) + (8 << 20));   // 64 MB

  wt_kernel<<<FF * FF / 256, 256, 0, stream>>>(W, WT);
  degconv_kernel<<<BB * NN / 4, 256, 0, stream>>>(adj, dis, adjBF);
  gemm1_kernel<<<256, 256, 0, stream>>>(x, WT, dis, gT);
  gemm2_kernel<<<256, 256, 0, stream>>>(adjBF, gT, bias, out);
}